// Round 11
// baseline (173.280 us; speedup 1.0000x reference)
//
#include <hip/hip_runtime.h>
#include <stdint.h>

// PSROIPool: fused, double-buffered, counted-vmcnt pipeline (T3/T4 pattern).
//
// c = d*49 + ph*7 + pw, so all 21 d-planes of a fixed (b,ph,pw) share the SAME
// roi geometry. Grid = 4*49*7 = 1372 blocks; each block owns (b,ph,pw) and 3
// consecutive d-planes, double-buffered in LDS:
//   1) preload 20 roi floats/lane to REGISTERS, sched-fence, THEN issue
//      stage(plane0) -> scan waits vmcnt(7) on its own loads, not a full drain
//      (R10's bug: roi loads issued after stage => every scan round drained
//      the whole stage due to vmcnt ordering);
//   2) scan+ballot-compact ONCE (per-wave segments, no atomics), hoist
//      per-lane roi params + float4 masks into registers (shared by 3 planes);
//   3) d-loop: raw s_barrier + counted s_waitcnt vmcnt(7): one 25.6 KB stage
//      always in flight under the previous plane's sum (no __syncthreads
//      full-drain anywhere in the loop).
//
// Rounding semantics mirror the reference exactly (verified R1-R10, absmax 7.8e-3).
// Assumes N == 1024 (problem-fixed; grid/scan layout hardcoded to 4 rounds).

#define PSB 4
#define PSC 1029
#define PSH 80
#define PSW 80
#define PSCALE 0.0625f
#define PLANE_F4 1600             // float4 per 80x80 plane
#define NMAX 1024
#define DCHUNK 3
#define NCHUNK 7                  // 21 / DCHUNK

typedef __attribute__((address_space(3))) void lds_void;
typedef __attribute__((address_space(1))) void glob_void;

#define VM_WAIT7() asm volatile("s_waitcnt vmcnt(7)" ::: "memory")
#define VM_WAIT0() asm volatile("s_waitcnt vmcnt(0)" ::: "memory")
#define BARRIER()  __builtin_amdgcn_s_barrier()
#define SFENCE()   __builtin_amdgcn_sched_barrier(0)

// Stage one plane: per wave a contiguous 400-float4 strip, 7 vmcnt events on
// EVERY wave (6 full + 1 with 16 active lanes) so vmcnt(7) is uniform+exact.
__device__ __forceinline__ void stage_plane(const float4* __restrict__ src4,
                                            float4* dst4, int wv, int lane)
{
    const int base = wv * 400;
    #pragma unroll
    for (int i = 0; i < 6; ++i) {
        int idx = base + i * 64 + lane;
        __builtin_amdgcn_global_load_lds((const glob_void*)(src4 + idx),
                                         (lds_void*)(dst4 + idx), 16, 0, 0);
    }
    int idx = base + 384 + lane;
    if (lane < 16)   // exec-masked, still 1 vmcnt event per wave (exec != 0)
        __builtin_amdgcn_global_load_lds((const glob_void*)(src4 + idx),
                                         (lds_void*)(dst4 + idx), 16, 0, 0);
}

__device__ __forceinline__ void make_masks(int ws, int we, int base,
                                           float4& m0, float4& m1,
                                           float4& m2, float4& m3)
{
#define MK(K) (((K) >= ws && (K) < we) ? 1.0f : 0.0f)
    m0 = make_float4(MK(base+0),  MK(base+1),  MK(base+2),  MK(base+3));
    m1 = make_float4(MK(base+4),  MK(base+5),  MK(base+6),  MK(base+7));
    m2 = make_float4(MK(base+8),  MK(base+9),  MK(base+10), MK(base+11));
    m3 = make_float4(MK(base+12), MK(base+13), MK(base+14), MK(base+15));
#undef MK
}

__device__ __forceinline__ float sum_roi(const float4* p4, int hs, int he,
                                         int a0, int nch,
                                         const float4& m0, const float4& m1,
                                         const float4& m2, const float4& m3)
{
    float s = 0.0f;
    for (int h = hs; h < he; ++h) {
        const float4* rw = p4 + h * (PSW / 4) + a0;
        float4 v = rw[0];
        s = fmaf(v.x, m0.x, s); s = fmaf(v.y, m0.y, s);
        s = fmaf(v.z, m0.z, s); s = fmaf(v.w, m0.w, s);
        if (nch > 1) {
            v = rw[1];
            s = fmaf(v.x, m1.x, s); s = fmaf(v.y, m1.y, s);
            s = fmaf(v.z, m1.z, s); s = fmaf(v.w, m1.w, s);
        }
        if (nch > 2) {
            v = rw[2];
            s = fmaf(v.x, m2.x, s); s = fmaf(v.y, m2.y, s);
            s = fmaf(v.z, m2.z, s); s = fmaf(v.w, m2.w, s);
        }
        if (nch > 3) {
            v = rw[3];
            s = fmaf(v.x, m3.x, s); s = fmaf(v.y, m3.y, s);
            s = fmaf(v.z, m3.z, s); s = fmaf(v.w, m3.w, s);
        }
    }
    return s;
}

__global__ __launch_bounds__(256) void psroi_pipe(
    const float* __restrict__ x,     // [B, C, H, W]
    const float* __restrict__ rois,  // [N, 5]
    float* __restrict__ out,         // [N, C]
    int N)
{
    const int blk   = blockIdx.x;          // (b*49 + pp)*7 + chunk
    const int chunk = blk % NCHUNK;
    const int t     = blk / NCHUNK;
    const int pp    = t % 49;
    const int b     = t / 49;
    const int ph    = pp / 7;
    const int pw    = pp % 7;
    const int d0    = chunk * DCHUNK;
    const int cb    = ph * 7 + pw;         // c(k) = (d0+k)*49 + cb

    __shared__ float4   bufA[PLANE_F4];    // 25600 B
    __shared__ float4   bufB[PLANE_F4];    // 25600 B
    __shared__ uint32_t geomL[NMAX];       //  4096 B
    __shared__ uint16_t nL[NMAX];          //  2048 B   -> 57344 B total

    const int tid  = threadIdx.x;
    const int lane = tid & 63;
    const int wv   = tid >> 6;

    const float* xb = x + (size_t)b * PSC * (PSH * PSW);
    const float4* src0 = (const float4*)(xb + (size_t)((d0 + 0) * 49 + cb) * (PSH * PSW));
    const float4* src1 = (const float4*)(xb + (size_t)((d0 + 1) * 49 + cb) * (PSH * PSW));
    const float4* src2 = (const float4*)(xb + (size_t)((d0 + 2) * 49 + cb) * (PSH * PSW));

    // ---- 1) roi register preload (BEFORE any stage: fixes vmcnt ordering) ----
    float rb[4][5];
    #pragma unroll
    for (int j = 0; j < 4; ++j) {
        const float* r = rois + (size_t)(j * 256 + wv * 64 + lane) * 5;
        rb[j][0] = r[0]; rb[j][1] = r[1]; rb[j][2] = r[2];
        rb[j][3] = r[3]; rb[j][4] = r[4];
    }
    SFENCE();

    // ---- 2) issue stage(plane 0 -> bufA); stays in flight through the scan ----
    stage_plane(src0, bufA, wv, lane);
    SFENCE();

    // ---- 3) scan + ballot-compact (register inputs only) ----
    const float fph = (float)ph, fpw = (float)pw;
    const int segBase = wv * 256;
    int segCnt = 0;
    #pragma unroll
    for (int j = 0; j < 4; ++j) {
        int n = j * 256 + wv * 64 + lane;
        bool match = ((int)rb[j][0] == b);

        float roi_sw = floorf(rb[j][1] + 0.5f) * PSCALE;
        float roi_sh = floorf(rb[j][2] + 0.5f) * PSCALE;
        float roi_ew = floorf(rb[j][3] + 1.5f) * PSCALE;   // rnd(x2 + 1.0)
        float roi_eh = floorf(rb[j][4] + 1.5f) * PSCALE;

        float bin_h = fmaxf(roi_eh - roi_sh, 0.1f) * (1.0f / 7.0f);
        float bin_w = fmaxf(roi_ew - roi_sw, 0.1f) * (1.0f / 7.0f);

        int hs = (int)fminf(fmaxf(floorf(fph * bin_h + roi_sh), 0.0f), (float)PSH);
        int he = (int)fminf(fmaxf(ceilf((fph + 1.0f) * bin_h + roi_sh), 0.0f), (float)PSH);
        int ws = (int)fminf(fmaxf(floorf(fpw * bin_w + roi_sw), 0.0f), (float)PSW);
        int we = (int)fminf(fmaxf(ceilf((fpw + 1.0f) * bin_w + roi_sw), 0.0f), (float)PSW);

        uint32_t pack = (uint32_t)hs | ((uint32_t)he << 8) |
                        ((uint32_t)ws << 16) | ((uint32_t)we << 24);

        unsigned long long mask = __ballot(match);
        int off = __popcll(mask & ((1ull << lane) - 1ull));
        if (match) {
            int s = segBase + segCnt + off;
            geomL[s] = pack;
            nL[s]    = (uint16_t)n;
        }
        segCnt += (int)__popcll(mask);
    }

    // ---- 4) hoist per-lane roi params + masks (same-wave LDS, no barrier) ----
    const bool has0 = lane < segCnt;
    const bool has1 = (64 + lane) < segCnt;

    int hs0=0, he0=0, a00=0, nch0=0, n0=0, area0=0;
    float inv0 = 0.0f; float4 m00, m01, m02, m03;
    m00 = m01 = m02 = m03 = make_float4(0, 0, 0, 0);
    if (has0) {
        uint32_t g = geomL[segBase + lane];
        n0 = nL[segBase + lane];
        hs0 = g & 0xFF; he0 = (g >> 8) & 0xFF;
        int ws = (g >> 16) & 0xFF, we = g >> 24;
        a00 = ws >> 2;
        nch0 = (we > ws) ? (((we - 1) >> 2) - a00 + 1) : 0;
        make_masks(ws, we, a00 * 4, m00, m01, m02, m03);
        area0 = (he0 - hs0) * (we - ws);
        inv0 = 1.0f / (float)(area0 > 0 ? area0 : 1);
    }
    int hs1=0, he1=0, a10=0, nch1=0, n1=0, area1=0;
    float inv1 = 0.0f; float4 m10, m11, m12, m13;
    m10 = m11 = m12 = m13 = make_float4(0, 0, 0, 0);
    if (has1) {
        uint32_t g = geomL[segBase + 64 + lane];
        n1 = nL[segBase + 64 + lane];
        hs1 = g & 0xFF; he1 = (g >> 8) & 0xFF;
        int ws = (g >> 16) & 0xFF, we = g >> 24;
        a10 = ws >> 2;
        nch1 = (we > ws) ? (((we - 1) >> 2) - a10 + 1) : 0;
        make_masks(ws, we, a10 * 4, m10, m11, m12, m13);
        area1 = (he1 - hs1) * (we - ws);
        inv1 = 1.0f / (float)(area1 > 0 ? area1 : 1);
    }

    auto sum_plane = [&](const float4* p4, int c) {
        if (has0) {
            float s = sum_roi(p4, hs0, he0, a00, nch0, m00, m01, m02, m03);
            out[(size_t)n0 * PSC + c] = (area0 > 0) ? s * inv0 : 0.0f;
        }
        if (has1) {
            float s = sum_roi(p4, hs1, he1, a10, nch1, m10, m11, m12, m13);
            out[(size_t)n1 * PSC + c] = (area1 > 0) ? s * inv1 : 0.0f;
        }
        for (int i = 128 + lane; i < segCnt; i += 64) {   // rare skew fallback
            uint32_t g = geomL[segBase + i];
            int n  = nL[segBase + i];
            int hs = g & 0xFF, he = (g >> 8) & 0xFF;
            int ws = (g >> 16) & 0xFF, we = g >> 24;
            int a0 = ws >> 2;
            int nch = (we > ws) ? (((we - 1) >> 2) - a0 + 1) : 0;
            float4 q0, q1, q2, q3;
            make_masks(ws, we, a0 * 4, q0, q1, q2, q3);
            float s = sum_roi(p4, hs, he, a0, nch, q0, q1, q2, q3);
            int area = (he - hs) * (we - ws);
            out[(size_t)n * PSC + c] = (area > 0) ? s / (float)area : 0.0f;
        }
    };

    // ---- 5) pipelined d-loop: counted vmcnt, raw barriers (no full drain) ----
    stage_plane(src1, bufB, wv, lane);      // 14 outstanding
    VM_WAIT7();                             // stage0 done (7 newer in flight)
    BARRIER(); SFENCE();
    sum_plane((const float4*)bufA, (d0 + 0) * 49 + cb);

    BARRIER(); SFENCE();                    // all waves done reading bufA
    stage_plane(src2, bufA, wv, lane);
    VM_WAIT7();                             // stage1 done
    BARRIER(); SFENCE();
    sum_plane((const float4*)bufB, (d0 + 1) * 49 + cb);

    VM_WAIT0();                             // stage2 done
    BARRIER(); SFENCE();
    sum_plane((const float4*)bufA, (d0 + 2) * 49 + cb);
}

extern "C" void kernel_launch(void* const* d_in, const int* in_sizes, int n_in,
                              void* d_out, int out_size, void* d_ws, size_t ws_size,
                              hipStream_t stream) {
    const float* x    = (const float*)d_in[0];
    const float* rois = (const float*)d_in[1];
    float* out        = (float*)d_out;
    int N = in_sizes[1] / 5;   // 1024 (scan layout assumes exactly 1024)

    psroi_pipe<<<PSB * 49 * NCHUNK, 256, 0, stream>>>(x, rois, out, N);
}

// Round 12
// 157.051 us; speedup vs baseline: 1.1033x; 1.1033x over previous
//
#include <hip/hip_runtime.h>
#include <stdint.h>

// PSROIPool: fused kernel, REG-STAGED plane (A/B test vs global_load_lds).
//
// R2..R11 all pinned at ~60-64 us kernel time with per-CU staging throughput
// constant at ~3.85 us/plane regardless of occupancy, pipelining, or VALU
// load. Common factor: global_load_lds on cold-HBM bytes. This round swaps
// ONLY the staging path: per-thread global float4 -> VGPR (issued early,
// latency hidden under the roi scan, T14) -> ds_write_b128 (late).
//
// Structure otherwise identical to R10's fused kernel:
//  1) preload 20 roi floats/lane to registers (FIRST, so the scan's waitcnt
//     doesn't drain the stage);
//  2) issue 7 float4 stage loads into VGPRs;
//  3) scan + ballot-compact batch-b rois into per-wave LDS segments
//     (overlaps stage-load latency);
//  4) ds_write staged regs -> plane, __syncthreads;
//  5) masked-float4 region sum from LDS, scatter write out[n*C+c].
//
// Rounding semantics mirror the reference exactly (verified R1-R11, absmax 7.8e-3).
// Assumes N == 1024 (scan layout hardcoded to 4 rounds of 256).

#define PSB 4
#define PSC 1029
#define PSH 80
#define PSW 80
#define PSCALE 0.0625f
#define PLANE_ELEMS (PSH * PSW)   // 6400
#define PLANE_F4 1600
#define NMAX 1024

__global__ __launch_bounds__(256) void psroi_fused_reg(
    const float* __restrict__ x,     // [B, C, H, W]
    const float* __restrict__ rois,  // [N, 5]
    float* __restrict__ out,         // [N, C]
    int N)
{
    const int blk = blockIdx.x;      // 0 .. B*C-1
    const int b   = blk / PSC;
    const int c   = blk - b * PSC;
    const int ph  = (c / 7) % 7;
    const int pw  = c % 7;

    __shared__ float    plane[PLANE_ELEMS];   // 25600 B
    __shared__ uint32_t geomL[NMAX];          //  4096 B
    __shared__ uint16_t nL[NMAX];             //  2048 B  -> 31744 B total

    const int tid  = threadIdx.x;
    const int lane = tid & 63;
    const int wv   = tid >> 6;

    // ---- 1) roi register preload FIRST (tiny; completes before stage) ----
    float rb[4][5];
    #pragma unroll
    for (int j = 0; j < 4; ++j) {
        const float* r = rois + (size_t)(j * 256 + wv * 64 + lane) * 5;
        rb[j][0] = r[0]; rb[j][1] = r[1]; rb[j][2] = r[2];
        rb[j][3] = r[3]; rb[j][4] = r[4];
    }

    // ---- 2) issue stage loads into VGPRs (latency hides under scan) ----
    const float4* __restrict__ src4 =
        (const float4*)(x + ((size_t)b * PSC + c) * PLANE_ELEMS);
    float4 v0 = src4[tid];
    float4 v1 = src4[tid + 256];
    float4 v2 = src4[tid + 512];
    float4 v3 = src4[tid + 768];
    float4 v4 = src4[tid + 1024];
    float4 v5 = src4[tid + 1280];
    float4 v6 = (tid < 64) ? src4[tid + 1536] : make_float4(0, 0, 0, 0);

    // ---- 3) scan + ballot-compact (register inputs only) ----
    const float fph = (float)ph, fpw = (float)pw;
    const int segBase = wv * 256;
    int segCnt = 0;
    #pragma unroll
    for (int j = 0; j < 4; ++j) {
        int n = j * 256 + wv * 64 + lane;
        bool match = ((int)rb[j][0] == b);

        float roi_sw = floorf(rb[j][1] + 0.5f) * PSCALE;
        float roi_sh = floorf(rb[j][2] + 0.5f) * PSCALE;
        float roi_ew = floorf(rb[j][3] + 1.5f) * PSCALE;   // rnd(x2 + 1.0)
        float roi_eh = floorf(rb[j][4] + 1.5f) * PSCALE;

        float bin_h = fmaxf(roi_eh - roi_sh, 0.1f) * (1.0f / 7.0f);
        float bin_w = fmaxf(roi_ew - roi_sw, 0.1f) * (1.0f / 7.0f);

        int hs = (int)fminf(fmaxf(floorf(fph * bin_h + roi_sh), 0.0f), (float)PSH);
        int he = (int)fminf(fmaxf(ceilf((fph + 1.0f) * bin_h + roi_sh), 0.0f), (float)PSH);
        int ws = (int)fminf(fmaxf(floorf(fpw * bin_w + roi_sw), 0.0f), (float)PSW);
        int we = (int)fminf(fmaxf(ceilf((fpw + 1.0f) * bin_w + roi_sw), 0.0f), (float)PSW);

        uint32_t pack = (uint32_t)hs | ((uint32_t)he << 8) |
                        ((uint32_t)ws << 16) | ((uint32_t)we << 24);

        unsigned long long mask = __ballot(match);
        int off = __popcll(mask & ((1ull << lane) - 1ull));
        if (match) {
            int s = segBase + segCnt + off;
            geomL[s] = pack;
            nL[s]    = (uint16_t)n;
        }
        segCnt += (int)__popcll(mask);
    }

    // ---- 4) write staged regs to LDS, then barrier ----
    {
        float4* dst4 = (float4*)plane;
        dst4[tid]        = v0;
        dst4[tid + 256]  = v1;
        dst4[tid + 512]  = v2;
        dst4[tid + 768]  = v3;
        dst4[tid + 1024] = v4;
        dst4[tid + 1280] = v5;
        if (tid < 64) dst4[tid + 1536] = v6;
    }
    __syncthreads();

    // ---- 5) process this wave's own segment ----
    const float4* __restrict__ p4 = (const float4*)plane;

    for (int i = lane; i < segCnt; i += 64) {
        uint32_t g = geomL[segBase + i];
        int n  = nL[segBase + i];
        int hs = g & 0xFF, he = (g >> 8) & 0xFF;
        int ws = (g >> 16) & 0xFF, we = g >> 24;

        int a0   = ws >> 2;
        int nch  = (we > ws) ? (((we - 1) >> 2) - a0 + 1) : 0;   // 0..4
        int base = a0 * 4;

        float4 m0, m1, m2, m3;
        {
            int k;
            k = base;      m0.x = (k>=ws && k<we); k++; m0.y = (k>=ws && k<we); k++;
                           m0.z = (k>=ws && k<we); k++; m0.w = (k>=ws && k<we);
            k = base + 4;  m1.x = (k>=ws && k<we); k++; m1.y = (k>=ws && k<we); k++;
                           m1.z = (k>=ws && k<we); k++; m1.w = (k>=ws && k<we);
            k = base + 8;  m2.x = (k>=ws && k<we); k++; m2.y = (k>=ws && k<we); k++;
                           m2.z = (k>=ws && k<we); k++; m2.w = (k>=ws && k<we);
            k = base + 12; m3.x = (k>=ws && k<we); k++; m3.y = (k>=ws && k<we); k++;
                           m3.z = (k>=ws && k<we); k++; m3.w = (k>=ws && k<we);
        }

        float s = 0.0f;
        for (int h = hs; h < he; ++h) {
            const float4* rw = p4 + h * (PSW / 4) + a0;
            {
                float4 v = rw[0];
                s = fmaf(v.x, m0.x, s); s = fmaf(v.y, m0.y, s);
                s = fmaf(v.z, m0.z, s); s = fmaf(v.w, m0.w, s);
            }
            if (nch > 1) {
                float4 v = rw[1];
                s = fmaf(v.x, m1.x, s); s = fmaf(v.y, m1.y, s);
                s = fmaf(v.z, m1.z, s); s = fmaf(v.w, m1.w, s);
            }
            if (nch > 2) {
                float4 v = rw[2];
                s = fmaf(v.x, m2.x, s); s = fmaf(v.y, m2.y, s);
                s = fmaf(v.z, m2.z, s); s = fmaf(v.w, m2.w, s);
            }
            if (nch > 3) {
                float4 v = rw[3];
                s = fmaf(v.x, m3.x, s); s = fmaf(v.y, m3.y, s);
                s = fmaf(v.z, m3.z, s); s = fmaf(v.w, m3.w, s);
            }
        }

        int area = (he - hs) * (we - ws);
        out[(size_t)n * PSC + c] = (area > 0) ? s / (float)area : 0.0f;
    }
}

extern "C" void kernel_launch(void* const* d_in, const int* in_sizes, int n_in,
                              void* d_out, int out_size, void* d_ws, size_t ws_size,
                              hipStream_t stream) {
    const float* x    = (const float*)d_in[0];
    const float* rois = (const float*)d_in[1];
    float* out        = (float*)d_out;
    int N = in_sizes[1] / 5;   // 1024

    psroi_fused_reg<<<PSB * PSC, 256, 0, stream>>>(x, rois, out, N);
}